// Round 7
// baseline (347.513 us; speedup 1.0000x reference)
//
#include <hip/hip_runtime.h>
#include <stdint.h>

// Problem constants: x[4,64,256,512] fp32, idx[3*256*3*512] i32 (harness converts i64->i32),
// w[64,64,3,3] fp32, bias[64] fp32. out[4,64,256,512] fp32.
#define HW_   131072   // 256*512 = 1<<17
#define W_    512
#define C_    64
#define KDIM  576      // 9 taps * 64 channels

typedef __bf16 bf16_t;
typedef bf16_t bf16x8 __attribute__((ext_vector_type(8)));
typedef float  f32x4_t __attribute__((ext_vector_type(4)));
typedef float  f32x2_t __attribute__((ext_vector_type(2)));
typedef unsigned u32x4 __attribute__((ext_vector_type(4)));

__device__ __forceinline__ unsigned short f32_to_bf16(float f) {
    union { float f; unsigned u; } v; v.f = f;
    unsigned r = (v.u + 0x7FFFu + ((v.u >> 16) & 1u)) >> 16;  // RNE
    return (unsigned short)r;
}

// Pack two f32 -> two bf16 in one dword via compiler casts (RNE).
__device__ __forceinline__ unsigned pack_bf16(float a, float b) {
    union { unsigned u; __bf16 h[2]; } pk;
    pk.h[0] = (__bf16)a;
    pk.h[1] = (__bf16)b;
    return pk.u;
}

// ws layout: xt bf16 [B*HW][64] at offset 0 (67,108,864 B); Wfrag bf16 at +XT_BYTES (73,728 B)
#define XT_BYTES   67108864ull
#define WF_BYTES   73728ull

// ---------------------------------------------------------------------------
// Pack weight[o][c][kh][kw] fp32 -> B-operand fragments, K-order k = t*64 + c, t = kh*3+kw.
// Fragment (kc, nt): lane L holds B[k = kc*32 + (L>>4)*8 + j][n = nt*16 + (L&15)], j=0..7.
// ---------------------------------------------------------------------------
__global__ __launch_bounds__(256) void k_prep_w(const float* __restrict__ w,
                                                unsigned short* __restrict__ wfrag) {
    int id = blockIdx.x * 256 + threadIdx.x;   // (kc*4 + nt)*64 + lane, total 18*4*64 = 4608
    if (id >= 18 * 4 * 64) return;
    int lane = id & 63;
    int nt   = (id >> 6) & 3;
    int kc   = id >> 8;
    int n  = nt * 16 + (lane & 15);
    int k0 = kc * 32 + ((lane >> 4) << 3);
    unsigned short tmp[8];
#pragma unroll
    for (int j = 0; j < 8; ++j) {
        int k = k0 + j;
        int t = k >> 6;    // tap 0..8
        int c = k & 63;
        tmp[j] = f32_to_bf16(w[(size_t)n * KDIM + c * 9 + t]);
    }
    uint4 v;
    v.x = tmp[0] | ((unsigned)tmp[1] << 16);
    v.y = tmp[2] | ((unsigned)tmp[3] << 16);
    v.z = tmp[4] | ((unsigned)tmp[5] << 16);
    v.w = tmp[6] | ((unsigned)tmp[7] << 16);
    ((uint4*)wfrag)[id] = v;
}

// ---------------------------------------------------------------------------
// Transpose + convert via LDS: x[b][c][p] fp32 -> xt[(b*HW+p)][c] bf16.
// Phase 1: float2 reads (8 B/lane), packed bf16 convert, ds_write_b32.
// Phase 2: row-major reads, coalesced lane-contiguous 16 B stores.
// ---------------------------------------------------------------------------
__global__ __launch_bounds__(256) void k_transpose(const float* __restrict__ x,
                                                   unsigned short* __restrict__ xt) {
    __shared__ unsigned short tile[256][66];
    int t    = threadIdx.x;
    int lane = t & 63;
    int wave = t >> 6;
    int gp0 = blockIdx.x * 256;                // grid = 2048
    int b  = gp0 >> 17;
    int p0 = gp0 & (HW_ - 1);
    const float* xb = x + ((size_t)b * C_) * HW_ + p0;
#pragma unroll
    for (int it = 0; it < 16; ++it) {
        int c0  = (it & 7) * 8 + wave * 2;     // even channels 0..62, 2 per thread
        int px0 = ((it >> 3) << 7) + lane * 2; // 2 consecutive pixels per thread
        const float* s0 = xb + ((size_t)c0 << 17) + px0;
        f32x2_t v0 = *(const f32x2_t*)s0;
        f32x2_t v1 = *(const f32x2_t*)(s0 + HW_);
        *(unsigned*)&tile[px0 + 0][c0] = pack_bf16(v0.x, v1.x);
        *(unsigned*)&tile[px0 + 1][c0] = pack_bf16(v0.y, v1.y);
    }
    __syncthreads();
    unsigned short* dst = xt + (size_t)gp0 * C_;
#pragma unroll
    for (int it = 0; it < 8; ++it) {
        int cid = it * 256 + t;        // 2048 chunks of 16 B
        int px  = cid >> 3;
        int ch  = cid & 7;
        uint4 v;
        v.x = *(unsigned*)&tile[px][ch * 8 + 0];
        v.y = *(unsigned*)&tile[px][ch * 8 + 2];
        v.z = *(unsigned*)&tile[px][ch * 8 + 4];
        v.w = *(unsigned*)&tile[px][ch * 8 + 6];
        ((uint4*)(dst + (size_t)px * C_))[ch] = v;   // lane-contiguous across the wave
    }
}

// ---------------------------------------------------------------------------
// Gather-GEMM v6: v4-verified depth-8 asm gather pipeline, occupancy doubled by
// HALVING LDS (not growing the block -- v5's 512-thread/128-VGPR-cap variant
// crashed: un-spillable asm-earlyclobber tuples vs the launch-bounds cap).
//  - B for kc 0..7: LDS (32 KiB -> 5 blocks/CU by LDS; ~4 by VGPR => 16 waves/CU).
//  - B for kc 8..17: through the asm vmcnt FIFO, issued lead-2, placed BEFORE the
//    A-issue so the retire point is B(s) without truncating A's depth-8 lead.
//  - Wait counts enumerated over the full 76-load FIFO (verified by position):
//    steps 0-6: 14; step 7: 18; steps 8-17: 8,8,8,6,4,4,4,4,4,0.
// Geometry unchanged from v4: grid 4096 x 256, 128 px/block, launch_bounds(256,2).
// ---------------------------------------------------------------------------
__global__ __launch_bounds__(256, 2) void k_gemm(const unsigned short* __restrict__ xt,
                                                 const unsigned short* __restrict__ wfrag,
                                                 const int* __restrict__ idx,
                                                 const float* __restrict__ bias,
                                                 float* __restrict__ out) {
    __shared__ u32x4 blds[2048];   // 32768 B: B-frags for kc = 0..7

    int tid  = threadIdx.x;
    int wave = tid >> 6;
    int lane = tid & 63;
    int bid  = blockIdx.x;
    int gbase = (((bid & 7) << 9) + (bid >> 3)) * 128;  // XCD-chunked swizzle (4096%8==0)
    int b = gbase >> 17;

    int quad = lane >> 4;
    int col  = lane & 15;
    int pxw  = wave * 32;

    // ---- stage B fragments (kc 0..7) into LDS; coalesced 16B loads ----
    {
        const u32x4* wfv = (const u32x4*)wfrag;
#pragma unroll
        for (int i = 0; i < 8; ++i)
            blds[i * 256 + tid] = wfv[i * 256 + tid];
    }

    // ---- gather indices: per-lane direct loads (no LDS) ----
    unsigned p_reg[9][2];
#pragma unroll
    for (int ms = 0; ms < 2; ++ms) {
        int g  = gbase + pxw + ms * 16 + col;
        int hw = g & (HW_ - 1);
        int h = hw >> 9, w = hw & (W_ - 1);
        const int* ib = idx + (size_t)(3 * h) * (3 * W_) + 3 * w;
#pragma unroll
        for (int t = 0; t < 9; ++t)
            p_reg[t][ms] = (unsigned)ib[(t / 3) * (3 * W_) + (t % 3)];
    }

    __syncthreads();   // drains ALL compiler vmem loads -> vmcnt FIFO empty

    const unsigned short* xtb = xt + (((size_t)b) << 17) * C_;
    const char* wfb = (const char*)wfrag;

    f32x4_t acc[2][4] = {};
    u32x4 Abuf[8][2];   // depth-8 asm pipeline (64 VGPR)
    u32x4 Bp[2][4];     // ping-pong LDS B fragments, kc 0..7 (32 VGPR)
    u32x4 Bf[2][4];     // ping-pong FIFO B fragments, kc 8..17 (32 VGPR)

#define GLOADX4(dst, addr)                                                       \
    asm volatile("global_load_dwordx4 %0, %1, off"                               \
                 : "=&v"(dst) : "v"((const void*)(addr)) : "memory")
#define WAITVM(n)                                                                \
    { asm volatile("s_waitcnt vmcnt(" #n ")" ::: "memory");                      \
      __builtin_amdgcn_sched_barrier(0); }
#define ISSUE_A(s)                                                               \
    { const int t_ = (s) >> 1, h_ = (s) & 1;                                     \
      GLOADX4(Abuf[(s) & 7][0], (const char*)xtb +                               \
              (((size_t)p_reg[t_][0] << 7) + (h_ << 6) + (quad << 4)));          \
      GLOADX4(Abuf[(s) & 7][1], (const char*)xtb +                               \
              (((size_t)p_reg[t_][1] << 7) + (h_ << 6) + (quad << 4))); }
#define ISSUE_BF(s)                                                              \
    { _Pragma("unroll")                                                          \
      for (int nt = 0; nt < 4; ++nt)                                             \
          GLOADX4(Bf[(s) & 1][nt],                                               \
                  wfb + (size_t)(((s) * 4 + nt) * 64 + lane) * 16); }
#define READ_B(s)                                                                \
    { _Pragma("unroll")                                                          \
      for (int nt = 0; nt < 4; ++nt)                                             \
          Bp[(s) & 1][nt] = blds[((s) * 4 + nt) * 64 + lane]; }
#define MFMA8(s, BSRC)                                                           \
    { _Pragma("unroll")                                                          \
      for (int ms = 0; ms < 2; ++ms)                                             \
      _Pragma("unroll")                                                          \
      for (int nt = 0; nt < 4; ++nt)                                             \
          acc[ms][nt] = __builtin_amdgcn_mfma_f32_16x16x32_bf16(                 \
              __builtin_bit_cast(bf16x8, Abuf[(s) & 7][ms]),                     \
              __builtin_bit_cast(bf16x8, (BSRC)[nt]), acc[ms][nt], 0, 0, 0); }

    // ---- asm FIFO prologue: A pipeline fill, steps 0..7 (16 loads) ----
    ISSUE_A(0) ISSUE_A(1) ISSUE_A(2) ISSUE_A(3)
    ISSUE_A(4) ISSUE_A(5) ISSUE_A(6) ISSUE_A(7)

    READ_B(0)   // Bcur for step 0 (LDS)

    // ---- 18 steps; waits verified against the 76-load FIFO enumeration ----
    WAITVM(14) READ_B(1) MFMA8(0, Bp[0])              ISSUE_A(8)
    WAITVM(14) READ_B(2) MFMA8(1, Bp[1])              ISSUE_A(9)
    WAITVM(14) READ_B(3) MFMA8(2, Bp[0])              ISSUE_A(10)
    WAITVM(14) READ_B(4) MFMA8(3, Bp[1])              ISSUE_A(11)
    WAITVM(14) READ_B(5) MFMA8(4, Bp[0])              ISSUE_A(12)
    WAITVM(14) READ_B(6) MFMA8(5, Bp[1])              ISSUE_A(13)
    WAITVM(14) READ_B(7) MFMA8(6, Bp[0]) ISSUE_BF(8)  ISSUE_A(14)
    WAITVM(18)           MFMA8(7, Bp[1]) ISSUE_BF(9)  ISSUE_A(15)
    WAITVM(8)            MFMA8(8, Bf[0]) ISSUE_BF(10) ISSUE_A(16)
    WAITVM(8)            MFMA8(9, Bf[1]) ISSUE_BF(11) ISSUE_A(17)
    WAITVM(8)            MFMA8(10, Bf[0]) ISSUE_BF(12)
    WAITVM(6)            MFMA8(11, Bf[1]) ISSUE_BF(13)
    WAITVM(4)            MFMA8(12, Bf[0]) ISSUE_BF(14)
    WAITVM(4)            MFMA8(13, Bf[1]) ISSUE_BF(15)
    WAITVM(4)            MFMA8(14, Bf[0]) ISSUE_BF(16)
    WAITVM(4)            MFMA8(15, Bf[1]) ISSUE_BF(17)
    WAITVM(4)            MFMA8(16, Bf[0])
    WAITVM(0)            MFMA8(17, Bf[1])

#undef GLOADX4
#undef WAITVM
#undef ISSUE_A
#undef ISSUE_BF
#undef READ_B
#undef MFMA8

    // Epilogue: C/D layout col=lane&15 (n), row=quad*4+reg (m). Plain f32x4 stores.
#pragma unroll
    for (int nt = 0; nt < 4; ++nt) {
        int o = nt * 16 + col;
        float bv = bias[o];
#pragma unroll
        for (int ms = 0; ms < 2; ++ms) {
            int m0 = ms * 16 + quad * 4;
            int hw0 = (gbase + pxw + m0) & (HW_ - 1);
            f32x4_t v = acc[ms][nt];
            v.x += bv; v.y += bv; v.z += bv; v.w += bv;
            *(f32x4_t*)(out + (((size_t)(b * 64 + o)) << 17) + hw0) = v;
        }
    }
}

// ---------------------------------------------------------------------------
// Fallback path (ws too small): direct fp32, slow but correct, no workspace.
// ---------------------------------------------------------------------------
__global__ __launch_bounds__(256) void k_fallback(const float* __restrict__ x,
                                                  const int* __restrict__ idx,
                                                  const float* __restrict__ w,
                                                  const float* __restrict__ bias,
                                                  float* __restrict__ out) {
    size_t g = (size_t)blockIdx.x * 256 + threadIdx.x;   // (b*64+o)*HW + hw
    int hw = (int)(g & (HW_ - 1));
    int o  = (int)((g >> 17) & 63);
    int b  = (int)(g >> 23);
    int h = hw >> 9, ww = hw & (W_ - 1);
    size_t ibase = (size_t)(3 * h) * (3 * W_) + 3 * ww;
    int p[9];
#pragma unroll
    for (int th = 0; th < 3; ++th)
#pragma unroll
        for (int tw = 0; tw < 3; ++tw)
            p[th * 3 + tw] = idx[ibase + (size_t)th * (3 * W_) + tw];
    const float* xb = x + (size_t)b * C_ * HW_;
    const float* wo = w + (size_t)o * KDIM;
    float acc = bias[o];
    for (int c = 0; c < C_; ++c) {
        const float* xc = xb + (size_t)c * HW_;
        const float* wc = wo + c * 9;
#pragma unroll
        for (int t = 0; t < 9; ++t)
            acc += xc[p[t]] * wc[t];
    }
    out[g] = acc;
}

extern "C" void kernel_launch(void* const* d_in, const int* in_sizes, int n_in,
                              void* d_out, int out_size, void* d_ws, size_t ws_size,
                              hipStream_t stream) {
    const float* x    = (const float*)d_in[0];
    const int*   idx  = (const int*)d_in[1];     // harness delivers integer inputs as int32
    const float* w    = (const float*)d_in[2];
    const float* bias = (const float*)d_in[3];
    float* out = (float*)d_out;

    if (ws_size >= XT_BYTES + WF_BYTES) {
        unsigned short* xt    = (unsigned short*)d_ws;
        unsigned short* wfrag = (unsigned short*)((char*)d_ws + XT_BYTES);
        k_prep_w   <<<18,   256, 0, stream>>>(w, wfrag);
        k_transpose<<<2048, 256, 0, stream>>>(x, xt);
        k_gemm     <<<4096, 256, 0, stream>>>(xt, wfrag, idx, bias, out);
    } else {
        k_fallback<<<131072, 256, 0, stream>>>(x, idx, w, bias, out);
    }
}